// Round 18
// baseline (434.101 us; speedup 1.0000x reference)
//
#include <hip/hip_runtime.h>
#include <hip/hip_bf16.h>
#include <stdint.h>

#define HN 128      // hidden size
#define TSTEPS 250
#define ON 20       // output size
#define GK 700      // input size
#define NKT 22      // GEMM k-tiles of 32 (700 = 21*32 + 28, zero-padded)

typedef _Float16 h2 __attribute__((ext_vector_type(2)));
typedef _Float16 h8 __attribute__((ext_vector_type(8)));
typedef float f4 __attribute__((ext_vector_type(4)));

__device__ __forceinline__ uint32_t pack2u(float x, float y) {
    h2 p; p.x = (_Float16)x; p.y = (_Float16)y;
    return __builtin_bit_cast(uint32_t, p);
}

// ---------------------------------------------------------------------------
// Phase A: in1_ff[bt,h] = X[bt,:] . W_ih1[h,:] + b_ih1[h]
// M=64000, N=128, K=700(pad 704). f16 MFMA 16x16x32 (verified r12). FROZEN.
// ---------------------------------------------------------------------------
__global__ __launch_bounds__(256) void ff_gemm(const float* __restrict__ X,
                                               const float* __restrict__ W,
                                               const float* __restrict__ bias,
                                               float* __restrict__ out) {
    __shared__ __align__(16) uint32_t Xs[2][128][16];   // 8 KB x2 (f16 pairs)
    __shared__ __align__(16) uint32_t Ws[2][128][16];   // 8 KB x2
    const int tid   = threadIdx.x;
    const int w     = tid >> 6;
    const int lane  = tid & 63;
    const int m0    = blockIdx.x * 128;
    const int srow  = tid & 127;
    const int shalf = tid >> 7;
    const int lr    = lane & 15;
    const int lg    = lane >> 4;

    f4 acc[2][8];
#pragma unroll
    for (int m = 0; m < 2; ++m)
#pragma unroll
        for (int n = 0; n < 8; ++n) acc[m][n] = (f4){0.f, 0.f, 0.f, 0.f};

    float4 x4[4], w4[4];

#define LOADT(t)                                                               \
    {                                                                          \
        const int k0 = (t) * 32 + shalf * 16;                                  \
        if ((t) < 21 || shalf == 0) {                                          \
            _Pragma("unroll")                                                  \
            for (int q = 0; q < 4; ++q) {                                      \
                x4[q] = *(const float4*)&X[(size_t)(m0 + srow) * GK + k0 + q * 4]; \
                w4[q] = *(const float4*)&W[(size_t)srow * GK + k0 + q * 4];    \
            }                                                                  \
        } else {                                                               \
            _Pragma("unroll")                                                  \
            for (int q = 0; q < 3; ++q) {                                      \
                x4[q] = *(const float4*)&X[(size_t)(m0 + srow) * GK + k0 + q * 4]; \
                w4[q] = *(const float4*)&W[(size_t)srow * GK + k0 + q * 4];    \
            }                                                                  \
            x4[3] = (float4){0.f, 0.f, 0.f, 0.f};                              \
            w4[3] = (float4){0.f, 0.f, 0.f, 0.f};                              \
        }                                                                      \
    }
#define STORET(buf)                                                            \
    {                                                                          \
        _Pragma("unroll")                                                      \
        for (int q = 0; q < 4; ++q) {                                          \
            Xs[buf][srow][shalf * 8 + 2 * q]     = pack2u(x4[q].x, x4[q].y);   \
            Xs[buf][srow][shalf * 8 + 2 * q + 1] = pack2u(x4[q].z, x4[q].w);   \
            Ws[buf][srow][shalf * 8 + 2 * q]     = pack2u(w4[q].x, w4[q].y);   \
            Ws[buf][srow][shalf * 8 + 2 * q + 1] = pack2u(w4[q].z, w4[q].w);   \
        }                                                                      \
    }

    LOADT(0);
    STORET(0);
    __syncthreads();
    int cur = 0;
    for (int t = 0; t < NKT; ++t) {
        if (t + 1 < NKT) LOADT(t + 1);
        h8 a[2];
#pragma unroll
        for (int m = 0; m < 2; ++m) {
            const uint4 au = *(const uint4*)&Xs[cur][w * 32 + m * 16 + lr][lg * 4];
            a[m] = __builtin_bit_cast(h8, au);
        }
#pragma unroll
        for (int n = 0; n < 8; ++n) {
            const uint4 bu = *(const uint4*)&Ws[cur][n * 16 + lr][lg * 4];
            const h8 bf = __builtin_bit_cast(h8, bu);
            acc[0][n] = __builtin_amdgcn_mfma_f32_16x16x32_f16(a[0], bf, acc[0][n], 0, 0, 0);
            acc[1][n] = __builtin_amdgcn_mfma_f32_16x16x32_f16(a[1], bf, acc[1][n], 0, 0, 0);
        }
        if (t + 1 < NKT) STORET(cur ^ 1);
        __syncthreads();
        cur ^= 1;
    }

    float bv[8];
#pragma unroll
    for (int n = 0; n < 8; ++n) bv[n] = bias[n * 16 + lr];
#pragma unroll
    for (int m = 0; m < 2; ++m)
#pragma unroll
        for (int q = 0; q < 4; ++q) {
            const size_t row = (size_t)(m0 + w * 32 + m * 16 + lg * 4 + q);
#pragma unroll
            for (int n = 0; n < 8; ++n)
                out[row * HN + n * 16 + lr] = acc[m][n][q] + bv[n];
        }
#undef LOADT
#undef STORET
}

// ---------------------------------------------------------------------------
// recurrence helpers (verified r13-r17)
// ---------------------------------------------------------------------------
__device__ __forceinline__ float rlane(float v, int k) {
    return __int_as_float(__builtin_amdgcn_readlane(__float_as_int(v), k));
}

// quantize a 128-float row into LDS column j of WQ[8][stride] + reg scale
template <int STRIDE>
__device__ __forceinline__ void qrow_lds(const float* __restrict__ src,
                                         uint4 (*WQ)[STRIDE], int j, float& sc) {
    float amax = 0.f;
#pragma unroll
    for (int q = 0; q < 32; ++q) {
        float4 v = *(const float4*)&src[q * 4];
        amax = fmaxf(amax, fmaxf(fmaxf(fabsf(v.x), fabsf(v.y)),
                                 fmaxf(fabsf(v.z), fabsf(v.w))));
    }
    const float qs = (amax > 0.f) ? 127.f / amax : 0.f;
#pragma unroll
    for (int g = 0; g < 8; ++g) {
        uint32_t u[4];
#pragma unroll
        for (int e = 0; e < 4; ++e) {
            float4 v = *(const float4*)&src[g * 16 + e * 4];
            const int q0 = (int)rintf(v.x * qs), q1 = (int)rintf(v.y * qs);
            const int q2 = (int)rintf(v.z * qs), q3 = (int)rintf(v.w * qs);
            u[e] = (uint32_t)(q0 & 255) | ((uint32_t)(q1 & 255) << 8) |
                   ((uint32_t)(q2 & 255) << 16) | ((uint32_t)(q3 & 255) << 24);
        }
        uint4 w4; w4.x = u[0]; w4.y = u[1]; w4.z = u[2]; w4.w = u[3];
        WQ[g][j] = w4;
    }
    sc = (amax > 0.f) ? amax / 127.f : 0.f;
}

// 128-dot: LDS weight column j vs spike bytes sv[8]; 4 independent chains
template <int STRIDE>
__device__ __forceinline__ int mvql(const uint4 (*W)[STRIDE],
                                    const uint4 (&sv)[8], int j) {
    int a0 = 0, a1 = 0, a2 = 0, a3 = 0;
#pragma unroll
    for (int g = 0; g < 8; ++g) {
        const uint4 wq = W[g][j];
        a0 = __builtin_amdgcn_sdot4((int)wq.x, (int)sv[g].x, a0, false);
        a1 = __builtin_amdgcn_sdot4((int)wq.y, (int)sv[g].y, a1, false);
        a2 = __builtin_amdgcn_sdot4((int)wq.z, (int)sv[g].z, a2, false);
        a3 = __builtin_amdgcn_sdot4((int)wq.w, (int)sv[g].w, a3, false);
    }
    return (a0 + a1) + (a2 + a3);
}

__device__ __forceinline__ uint32_t nib2bytes(uint32_t nib) {
    return ((nib & 15u) * 0x00204081u) & 0x01010101u;
}

// spread a 128-bit spike mask (2 uniform u64 ballots) into dot-bytes
__device__ __forceinline__ void spread_masks(unsigned long long lo,
                                             unsigned long long hi,
                                             uint4 (&sv)[8]) {
#pragma unroll
    for (int g = 0; g < 8; ++g) {
        const unsigned long long src = (g < 4) ? lo : hi;
        const int base = (g & 3) * 16;
        sv[g].x = nib2bytes((uint32_t)(src >> (base + 0)));
        sv[g].y = nib2bytes((uint32_t)(src >> (base + 4)));
        sv[g].z = nib2bytes((uint32_t)(src >> (base + 8)));
        sv[g].w = nib2bytes((uint32_t)(src >> (base + 12)));
    }
}

// ---------------------------------------------------------------------------
// Phase B: MONOLITHIC single-wave recurrence. One wave (64 thr) per batch
// row; 256 blocks. All stages in-wave: zero barriers, zero LDS writes, zero
// cross-wave hops in the 250-step loop. Lane owns rows (lane, lane+64) of
// each layer; spikes live as ballot masks -> SALU spread -> uniform sdot4
// operands. rdot broadcast via v_readlane (VALU, cheap). Weights i8 in LDS
// (52 KB, lane reads only its own columns -> conflict-free); scales in regs.
// ---------------------------------------------------------------------------
__global__ __launch_bounds__(64) void srnn_mono(
    const float* __restrict__ ff,
    const float* __restrict__ W_h1h1, const float* __restrict__ b_h1h1,
    const float* __restrict__ W_h1h2, const float* __restrict__ b_h1h2,
    const float* __restrict__ W_h2h2, const float* __restrict__ b_h2h2,
    const float* __restrict__ W_h2o,  const float* __restrict__ b_h2o,
    const float* __restrict__ tau_adp_h1, const float* __restrict__ tau_adp_h2,
    const float* __restrict__ tau_m_h1,   const float* __restrict__ tau_m_h2,
    const float* __restrict__ tau_m_o,
    const float* __restrict__ h1m0, const float* __restrict__ h2m0,
    const float* __restrict__ om0,
    float* __restrict__ out) {
    const int b    = blockIdx.x;
    const int lane = threadIdx.x;
    const int jl = lane, jh = lane + 64;

    __shared__ __align__(16) uint4 WQA[8][HN];   // 16 KB
    __shared__ __align__(16) uint4 WQB[8][HN];   // 16 KB
    __shared__ __align__(16) uint4 WQC[8][HN];   // 16 KB
    __shared__ __align__(16) uint4 WQO[8][64];   //  8 KB

    // ---- stage + quantize (one time; lane writes only its own columns) ----
    float sAl, sAh, sBl, sBh, sCl, sCh, sO;
    qrow_lds<HN>(W_h1h1 + jl * HN, WQA, jl, sAl);
    qrow_lds<HN>(W_h1h1 + jh * HN, WQA, jh, sAh);
    qrow_lds<HN>(W_h1h2 + jl * HN, WQB, jl, sBl);
    qrow_lds<HN>(W_h1h2 + jh * HN, WQB, jh, sBh);
    qrow_lds<HN>(W_h2h2 + jl * HN, WQC, jl, sCl);
    qrow_lds<HN>(W_h2h2 + jh * HN, WQC, jh, sCh);
    qrow_lds<64>(W_h2o + (size_t)((lane < ON) ? lane : 0) * HN, WQO, lane, sO);
    if (lane >= ON) sO = 0.f;
    __syncthreads();   // one-time (single wave: just orders LDS writes/reads)

    // ---- per-lane state ----
    float h1m_l = h1m0[b * HN + jl], h1m_h = h1m0[b * HN + jh];
    const float a1l = expf(-1.f / tau_m_h1[jl]), a1h = expf(-1.f / tau_m_h1[jh]);
    const float r1l = expf(-1.f / tau_adp_h1[jl]), r1h = expf(-1.f / tau_adp_h1[jh]);
    const float bi1l = b_h1h1[jl], bi1h = b_h1h1[jh];
    float h2m_l = h2m0[b * HN + jl], h2m_h = h2m0[b * HN + jh];
    const float a2l = expf(-1.f / tau_m_h2[jl]), a2h = expf(-1.f / tau_m_h2[jh]);
    const float r2l = expf(-1.f / tau_adp_h2[jl]), r2h = expf(-1.f / tau_adp_h2[jh]);
    const float bi2l = b_h1h2[jl] + b_h2h2[jl];
    const float bi2h = b_h1h2[jh] + b_h2h2[jh];
    float b1l = 0.01f, b1h = 0.01f, s1l = 0.f, s1h = 0.f;
    float b2l = 0.01f, b2h = 0.01f, s2l = 0.f, s2h = 0.f;
    float om = 0.f, ao = 0.f, bo = 0.f, acc = 0.f;
    if (lane < ON) {
        om = om0[b * ON + lane];
        ao = expf(-1.f / tau_m_o[lane]);
        bo = b_h2o[lane];
    }

    const float* fpl = ff + (size_t)b * TSTEPS * HN + jl;
    const float* fph = ff + (size_t)b * TSTEPS * HN + jh;
    float fcl = fpl[0], fnl = fpl[HN];
    float fch = fph[0], fnh = fph[HN];

    uint4 sv1[8], sv2[8];
    spread_masks(0ull, 0ull, sv1);
    spread_masks(0ull, 0ull, sv2);

    for (int t = 0; t < TSTEPS; ++t) {
        const float f2l = (t + 2 < TSTEPS) ? fpl[(size_t)(t + 2) * HN] : 0.f;
        const float f2h = (t + 2 < TSTEPS) ? fph[(size_t)(t + 2) * HN] : 0.f;

        // ---- S1: uses s1(t-1) in sv1 ----
        const float pAl = sAl * (float)mvql<HN>(WQA, sv1, jl);
        const float pAh = sAh * (float)mvql<HN>(WQA, sv1, jh);
        b1l = r1l * b1l + (1.f - r1l) * s1l;
        b1h = r1h * b1h + (1.f - r1h) * s1h;
        const float Bt1l = 0.01f + 1.8f * b1l;
        const float Bt1h = 0.01f + 1.8f * b1h;
        h1m_l = h1m_l * a1l + (1.f - a1l) * (fcl + bi1l + pAl) - Bt1l * s1l;
        h1m_h = h1m_h * a1h + (1.f - a1h) * (fch + bi1h + pAh) - Bt1h * s1h;
        const int sp1l = (h1m_l - Bt1l > 0.f) ? 1 : 0;
        const int sp1h = (h1m_h - Bt1h > 0.f) ? 1 : 0;
        s1l = (float)sp1l; s1h = (float)sp1h;
        spread_masks(__ballot(sp1l), __ballot(sp1h), sv1);   // s1(t)

        // ---- L2: in2 = W_h1h2.s1(t) + W_h2h2.s2(t-1) + biases ----
        const float pBl = sBl * (float)mvql<HN>(WQB, sv1, jl);
        const float pBh = sBh * (float)mvql<HN>(WQB, sv1, jh);
        const float pCl = sCl * (float)mvql<HN>(WQC, sv2, jl);
        const float pCh = sCh * (float)mvql<HN>(WQC, sv2, jh);
        b2l = r2l * b2l + (1.f - r2l) * s2l;
        b2h = r2h * b2h + (1.f - r2h) * s2h;
        const float Bt2l = 0.01f + 1.8f * b2l;
        const float Bt2h = 0.01f + 1.8f * b2h;
        h2m_l = h2m_l * a2l + (1.f - a2l) * (pBl + pCl + bi2l) - Bt2l * s2l;
        h2m_h = h2m_h * a2h + (1.f - a2h) * (pBh + pCh + bi2h) - Bt2h * s2h;
        const int sp2l = (h2m_l - Bt2l > 0.f) ? 1 : 0;
        const int sp2h = (h2m_h - Bt2h > 0.f) ? 1 : 0;
        s2l = (float)sp2l; s2h = (float)sp2h;
        spread_masks(__ballot(sp2l), __ballot(sp2h), sv2);   // s2(t)

        // ---- RO: lane o computes rdot[o] = W_h2o[o] . s2(t) ----
        const float rdot = sO * (float)mvql<64>(WQO, sv2, lane);

        // ---- OM: per-lane leaky integrate; softmax via readlane bcast ----
        om = om * ao + (1.f - ao) * (rdot + bo);
        if (t > 10) {
            float omk[ON];
#pragma unroll
            for (int k = 0; k < ON; ++k) omk[k] = rlane(om, k);
            float m0 = omk[0], m1 = omk[1], m2 = omk[2], m3 = omk[3];
#pragma unroll
            for (int k = 4; k < ON; k += 4) {
                m0 = fmaxf(m0, omk[k]);
                m1 = fmaxf(m1, omk[k + 1]);
                m2 = fmaxf(m2, omk[k + 2]);
                m3 = fmaxf(m3, omk[k + 3]);
            }
            const float mx = fmaxf(fmaxf(m0, m1), fmaxf(m2, m3));
            float d0 = 0.f, d1 = 0.f, d2 = 0.f, d3 = 0.f;
#pragma unroll
            for (int k = 0; k < ON; k += 4) {
                d0 += __expf(omk[k] - mx);
                d1 += __expf(omk[k + 1] - mx);
                d2 += __expf(omk[k + 2] - mx);
                d3 += __expf(omk[k + 3] - mx);
            }
            const float den = (d0 + d1) + (d2 + d3);
            acc += __expf(om - mx) / den;     // valid on lanes < ON
        }
        fcl = fnl; fnl = f2l; fch = fnh; fnh = f2h;
    }

    if (lane < ON) out[b * ON + lane] = acc;
}

// ---------------------------------------------------------------------------
// Phase C: A_norm = sum|W_h1h1| + sum|W_h2h2|  -> out[5120]  (exact fp32)
// ---------------------------------------------------------------------------
__global__ void anorm_kernel(const float* __restrict__ W1,
                             const float* __restrict__ W2,
                             float* __restrict__ out) {
    __shared__ float red[256];
    float s = 0.f;
    for (int i = threadIdx.x; i < HN * HN; i += 256)
        s += fabsf(W1[i]) + fabsf(W2[i]);
    red[threadIdx.x] = s;
    __syncthreads();
    for (int off = 128; off > 0; off >>= 1) {
        if (threadIdx.x < off) red[threadIdx.x] += red[threadIdx.x + off];
        __syncthreads();
    }
    if (threadIdx.x == 0) out[256 * ON] = red[0];
}

extern "C" void kernel_launch(void* const* d_in, const int* in_sizes, int n_in,
                              void* d_out, int out_size, void* d_ws, size_t ws_size,
                              hipStream_t stream) {
    const float* input      = (const float*)d_in[0];
    // d_in[1], d_in[2]: A1_mask/A2_mask -- all-ones, unused by reference math
    const float* W_ih1      = (const float*)d_in[3];
    const float* b_ih1      = (const float*)d_in[4];
    const float* W_h1h1     = (const float*)d_in[5];
    const float* b_h1h1     = (const float*)d_in[6];
    const float* W_h1h2     = (const float*)d_in[7];
    const float* b_h1h2     = (const float*)d_in[8];
    const float* W_h2h2     = (const float*)d_in[9];
    const float* b_h2h2     = (const float*)d_in[10];
    const float* W_h2o      = (const float*)d_in[11];
    const float* b_h2o      = (const float*)d_in[12];
    const float* tau_adp_h1 = (const float*)d_in[13];
    const float* tau_adp_h2 = (const float*)d_in[14];
    const float* tau_m_h1   = (const float*)d_in[15];
    const float* tau_m_h2   = (const float*)d_in[16];
    const float* tau_m_o    = (const float*)d_in[17];
    const float* h1m0       = (const float*)d_in[18];
    const float* h2m0       = (const float*)d_in[19];
    const float* om0        = (const float*)d_in[20];

    float* out   = (float*)d_out;
    float* ffbuf = (float*)d_ws;   // 256*250*128*4 = 32.768 MB

    anorm_kernel<<<1, 256, 0, stream>>>(W_h1h1, W_h2h2, out);
    ff_gemm<<<500, 256, 0, stream>>>(input, W_ih1, b_ih1, ffbuf);
    srnn_mono<<<256, 64, 0, stream>>>(ffbuf, W_h1h1, b_h1h1, W_h1h2, b_h1h2,
                                      W_h2h2, b_h2h2, W_h2o, b_h2o,
                                      tau_adp_h1, tau_adp_h2,
                                      tau_m_h1, tau_m_h2, tau_m_o,
                                      h1m0, h2m0, om0, out);
}

// Round 19
// 230.879 us; speedup vs baseline: 1.8802x; 1.8802x over previous
//
#include <hip/hip_runtime.h>
#include <hip/hip_bf16.h>
#include <stdint.h>

#define HN 128      // hidden size
#define TSTEPS 250
#define ON 20       // output size
#define GK 700      // input size
#define NKT 22      // GEMM k-tiles of 32 (700 = 21*32 + 28, zero-padded)

typedef _Float16 h2 __attribute__((ext_vector_type(2)));
typedef _Float16 h8 __attribute__((ext_vector_type(8)));
typedef float f4 __attribute__((ext_vector_type(4)));

__device__ __forceinline__ uint32_t pack2u(float x, float y) {
    h2 p; p.x = (_Float16)x; p.y = (_Float16)y;
    return __builtin_bit_cast(uint32_t, p);
}

// ---------------------------------------------------------------------------
// Phase A: in1_ff[bt,h] = X[bt,:] . W_ih1[h,:] + b_ih1[h]
// M=64000, N=128, K=700(pad 704). f16 MFMA 16x16x32 (verified r12).
// OUTPUT NOW f16 (halves srnn staging; rounding ~1e-3 << tolerance).
// ---------------------------------------------------------------------------
__global__ __launch_bounds__(256) void ff_gemm(const float* __restrict__ X,
                                               const float* __restrict__ W,
                                               const float* __restrict__ bias,
                                               _Float16* __restrict__ out) {
    __shared__ __align__(16) uint32_t Xs[2][128][16];   // 8 KB x2 (f16 pairs)
    __shared__ __align__(16) uint32_t Ws[2][128][16];   // 8 KB x2
    const int tid   = threadIdx.x;
    const int w     = tid >> 6;
    const int lane  = tid & 63;
    const int m0    = blockIdx.x * 128;
    const int srow  = tid & 127;
    const int shalf = tid >> 7;
    const int lr    = lane & 15;
    const int lg    = lane >> 4;

    f4 acc[2][8];
#pragma unroll
    for (int m = 0; m < 2; ++m)
#pragma unroll
        for (int n = 0; n < 8; ++n) acc[m][n] = (f4){0.f, 0.f, 0.f, 0.f};

    float4 x4[4], w4[4];

#define LOADT(t)                                                               \
    {                                                                          \
        const int k0 = (t) * 32 + shalf * 16;                                  \
        if ((t) < 21 || shalf == 0) {                                          \
            _Pragma("unroll")                                                  \
            for (int q = 0; q < 4; ++q) {                                      \
                x4[q] = *(const float4*)&X[(size_t)(m0 + srow) * GK + k0 + q * 4]; \
                w4[q] = *(const float4*)&W[(size_t)srow * GK + k0 + q * 4];    \
            }                                                                  \
        } else {                                                               \
            _Pragma("unroll")                                                  \
            for (int q = 0; q < 3; ++q) {                                      \
                x4[q] = *(const float4*)&X[(size_t)(m0 + srow) * GK + k0 + q * 4]; \
                w4[q] = *(const float4*)&W[(size_t)srow * GK + k0 + q * 4];    \
            }                                                                  \
            x4[3] = (float4){0.f, 0.f, 0.f, 0.f};                              \
            w4[3] = (float4){0.f, 0.f, 0.f, 0.f};                              \
        }                                                                      \
    }
#define STORET(buf)                                                            \
    {                                                                          \
        _Pragma("unroll")                                                      \
        for (int q = 0; q < 4; ++q) {                                          \
            Xs[buf][srow][shalf * 8 + 2 * q]     = pack2u(x4[q].x, x4[q].y);   \
            Xs[buf][srow][shalf * 8 + 2 * q + 1] = pack2u(x4[q].z, x4[q].w);   \
            Ws[buf][srow][shalf * 8 + 2 * q]     = pack2u(w4[q].x, w4[q].y);   \
            Ws[buf][srow][shalf * 8 + 2 * q + 1] = pack2u(w4[q].z, w4[q].w);   \
        }                                                                      \
    }

    LOADT(0);
    STORET(0);
    __syncthreads();
    int cur = 0;
    for (int t = 0; t < NKT; ++t) {
        if (t + 1 < NKT) LOADT(t + 1);
        h8 a[2];
#pragma unroll
        for (int m = 0; m < 2; ++m) {
            const uint4 au = *(const uint4*)&Xs[cur][w * 32 + m * 16 + lr][lg * 4];
            a[m] = __builtin_bit_cast(h8, au);
        }
#pragma unroll
        for (int n = 0; n < 8; ++n) {
            const uint4 bu = *(const uint4*)&Ws[cur][n * 16 + lr][lg * 4];
            const h8 bf = __builtin_bit_cast(h8, bu);
            acc[0][n] = __builtin_amdgcn_mfma_f32_16x16x32_f16(a[0], bf, acc[0][n], 0, 0, 0);
            acc[1][n] = __builtin_amdgcn_mfma_f32_16x16x32_f16(a[1], bf, acc[1][n], 0, 0, 0);
        }
        if (t + 1 < NKT) STORET(cur ^ 1);
        __syncthreads();
        cur ^= 1;
    }

    float bv[8];
#pragma unroll
    for (int n = 0; n < 8; ++n) bv[n] = bias[n * 16 + lr];
#pragma unroll
    for (int m = 0; m < 2; ++m)
#pragma unroll
        for (int q = 0; q < 4; ++q) {
            const size_t row = (size_t)(m0 + w * 32 + m * 16 + lg * 4 + q);
#pragma unroll
            for (int n = 0; n < 8; ++n)
                out[row * HN + n * 16 + lr] = (_Float16)(acc[m][n][q] + bv[n]);
        }
#undef LOADT
#undef STORET
}

// ---------------------------------------------------------------------------
// i8 matvec helpers (verified r13): weights WQ[g][j] = uint4 of 16 i8;
// spike vector sv[8] wave-uniform packed 0/1 bytes.
// ---------------------------------------------------------------------------
__device__ __forceinline__ int mvq(const uint4 (&W)[8][HN],
                                   const uint4 (&sv)[8], int j) {
    int a0 = 0, a1 = 0, a2 = 0, a3 = 0;
#pragma unroll
    for (int g = 0; g < 8; ++g) {
        const uint4 wq = W[g][j];
        const uint4 sq = sv[g];
        a0 = __builtin_amdgcn_sdot4((int)wq.x, (int)sq.x, a0, false);
        a1 = __builtin_amdgcn_sdot4((int)wq.y, (int)sq.y, a1, false);
        a2 = __builtin_amdgcn_sdot4((int)wq.z, (int)sq.z, a2, false);
        a3 = __builtin_amdgcn_sdot4((int)wq.w, (int)sq.w, a3, false);
    }
    return (a0 + a1) + (a2 + a3);
}
__device__ __forceinline__ int mvqo(const uint4 (&W)[8][32],
                                    const uint4 (&sv)[8], int j) {
    int a0 = 0, a1 = 0, a2 = 0, a3 = 0;
#pragma unroll
    for (int g = 0; g < 8; ++g) {
        const uint4 wq = W[g][j];
        const uint4 sq = sv[g];
        a0 = __builtin_amdgcn_sdot4((int)wq.x, (int)sq.x, a0, false);
        a1 = __builtin_amdgcn_sdot4((int)wq.y, (int)sq.y, a1, false);
        a2 = __builtin_amdgcn_sdot4((int)wq.z, (int)sq.z, a2, false);
        a3 = __builtin_amdgcn_sdot4((int)wq.w, (int)sq.w, a3, false);
    }
    return (a0 + a1) + (a2 + a3);
}

#define LOADQ(arr, buf, sv)                                                    \
    {                                                                          \
        const uint4* _p = (const uint4*)&arr[buf][0];                          \
        _Pragma("unroll") for (int _g = 0; _g < 8; ++_g) sv[_g] = _p[_g];      \
    }

__device__ __forceinline__ uint32_t nib2bytes(uint32_t nib) {
    return ((nib & 15u) * 0x00204081u) & 0x01010101u;
}

// ---------------------------------------------------------------------------
// Phase B: r13's i8-LDS sdot4 barrier pipeline (best measured: 159 us) with
// ONE change: the entire ff trajectory for this row is preloaded to LDS as
// f16 (62.5 KB), so the 250-step loop has ZERO global loads -> __syncthreads
// no longer drains an in-flight HBM load every slot (vmcnt(0) stall removed).
// Roles (slot i, one barrier each):
//   w0,w1: S1 -> s1(i)   w2,w3: B -> pB(i-1)   w4,w5: C+L2 -> s2(i-2)
//   w6: RO -> rdot(i-3)  w7: OM -> om/softmax(i-4)
// ---------------------------------------------------------------------------
__global__ __launch_bounds__(512) void srnn_pipe14(
    const _Float16* __restrict__ ff,
    const float* __restrict__ W_h1h1, const float* __restrict__ b_h1h1,
    const float* __restrict__ W_h1h2, const float* __restrict__ b_h1h2,
    const float* __restrict__ W_h2h2, const float* __restrict__ b_h2h2,
    const float* __restrict__ W_h2o,  const float* __restrict__ b_h2o,
    const float* __restrict__ tau_adp_h1, const float* __restrict__ tau_adp_h2,
    const float* __restrict__ tau_m_h1,   const float* __restrict__ tau_m_h2,
    const float* __restrict__ tau_m_o,
    const float* __restrict__ h1m0, const float* __restrict__ h2m0,
    const float* __restrict__ om0,
    float* __restrict__ out) {
    const int b    = blockIdx.x;
    const int tid  = threadIdx.x;
    const int w    = tid >> 6;
    const int lane = tid & 63;

    __shared__ __align__(16) uint4 WQA[8][HN];   // 16 KB
    __shared__ __align__(16) uint4 WQB[8][HN];   // 16 KB
    __shared__ __align__(16) uint4 WQC[8][HN];   // 16 KB
    __shared__ __align__(16) uint4 WQO[8][32];   //  4 KB
    __shared__ float scA[HN], scB[HN], scC[HN], scO[32];
    __shared__ __align__(16) uint32_t s1w[2][32];
    __shared__ __align__(16) uint32_t s2w[2][32];
    __shared__ float pBbuf[2][HN];
    __shared__ __align__(16) float rdot_lds[2][32];
    __shared__ __align__(16) _Float16 ffh[TSTEPS][HN];   // 62.5 KB

    // ---- preload ff trajectory (f16, flat 4000 uint4) ----
    {
        const uint4* src = (const uint4*)(ff + (size_t)b * TSTEPS * HN);
        uint4* dst = (uint4*)&ffh[0][0];
        for (int e = tid; e < TSTEPS * HN / 8; e += 512) dst[e] = src[e];
    }

    // ---- stage: per-row i8 quantization (one time, verified r13) ----
    if (tid < 416) {
        const int role = tid >> 7;          // 0:A 1:B 2:C 3:O-block
        const int j    = tid & 127;
        const bool isO = (role == 3);
        const bool on  = !isO || (j < 32);
        if (on) {
            const float* src = nullptr;
            bool valid = true;
            if (!isO) {
                src = (role == 0 ? W_h1h1 : role == 1 ? W_h1h2 : W_h2h2) + j * HN;
            } else if (j < ON) {
                src = W_h2o + j * HN;
            } else {
                valid = false;
            }
            float amax = 0.f;
            if (valid) {
#pragma unroll
                for (int q = 0; q < 32; ++q) {
                    float4 v = *(const float4*)&src[q * 4];
                    amax = fmaxf(amax, fmaxf(fmaxf(fabsf(v.x), fabsf(v.y)),
                                             fmaxf(fabsf(v.z), fabsf(v.w))));
                }
            }
            const float qs = (valid && amax > 0.f) ? 127.f / amax : 0.f;
#pragma unroll
            for (int g = 0; g < 8; ++g) {
                uint32_t u[4] = {0u, 0u, 0u, 0u};
                if (valid) {
#pragma unroll
                    for (int e = 0; e < 4; ++e) {
                        float4 v = *(const float4*)&src[g * 16 + e * 4];
                        const int q0 = (int)rintf(v.x * qs), q1 = (int)rintf(v.y * qs);
                        const int q2 = (int)rintf(v.z * qs), q3 = (int)rintf(v.w * qs);
                        u[e] = (uint32_t)(q0 & 255) | ((uint32_t)(q1 & 255) << 8) |
                               ((uint32_t)(q2 & 255) << 16) | ((uint32_t)(q3 & 255) << 24);
                    }
                }
                uint4 w4; w4.x = u[0]; w4.y = u[1]; w4.z = u[2]; w4.w = u[3];
                if (isO) WQO[g][j] = w4;
                else if (role == 0) WQA[g][j] = w4;
                else if (role == 1) WQB[g][j] = w4;
                else WQC[g][j] = w4;
            }
            const float os = (valid && amax > 0.f) ? amax / 127.f : 0.f;
            if (isO) scO[j] = os;
            else if (role == 0) scA[j] = os;
            else if (role == 1) scB[j] = os;
            else scC[j] = os;
        }
    }
    if (tid < 32) {
        s1w[0][tid] = 0u; s1w[1][tid] = 0u;
        s2w[0][tid] = 0u; s2w[1][tid] = 0u;
    }
    __syncthreads();

    if (w < 2) {
        // ================= S1: layer-1 LIF, j = w*64+lane =================
        const int j = (w << 6) + lane;
        const float sA = scA[j];
        float h1m = h1m0[b * HN + j];
        const float a1 = expf(-1.f / tau_m_h1[j]);
        const float r1 = expf(-1.f / tau_adp_h1[j]);
        const float bi = b_h1h1[j];
        float b1 = 0.01f, s1p = 0.f;
        for (int i = 0; i < TSTEPS + 4; ++i) {
            if (i < TSTEPS) {
                const float fcv = (float)ffh[i][j];        // LDS, no vmcnt
                uint4 sv[8];
                LOADQ(s1w, (i + 1) & 1, sv);               // s1(i-1)
                const float pA = sA * (float)mvq(WQA, sv, j);
                b1 = r1 * b1 + (1.f - r1) * s1p;
                const float Bt = 0.01f + 1.8f * b1;
                h1m = h1m * a1 + (1.f - a1) * (fcv + bi + pA) - Bt * s1p;
                const int sp = (h1m - Bt > 0.f) ? 1 : 0;
                s1p = (float)sp;
                const unsigned long long mk = __ballot(sp);
                const uint32_t mlo = (uint32_t)mk, mhi = (uint32_t)(mk >> 32);
                if (lane < 16) {
                    const uint32_t nib = (lane < 8 ? mlo : mhi) >> ((lane & 7) * 4);
                    s1w[i & 1][(w << 4) + lane] = nib2bytes(nib);
                }
            }
            __syncthreads();
        }
    } else if (w < 4) {
        // ================= B: pB(i-1) = W_h1h2 . s1(i-1) =================
        const int j = ((w - 2) << 6) + lane;
        const float sB = scB[j];
        for (int i = 0; i < TSTEPS + 4; ++i) {
            if (i >= 1 && i <= TSTEPS) {
                uint4 sv[8];
                LOADQ(s1w, (i - 1) & 1, sv);
                pBbuf[(i - 1) & 1][j] = sB * (float)mvq(WQB, sv, j);
            }
            __syncthreads();
        }
    } else if (w < 6) {
        // ================= C + LIF2: s2(i-2), j = (w-4)*64+lane ============
        const int j = ((w - 4) << 6) + lane;
        const float sC = scC[j];
        float h2m = h2m0[b * HN + j];
        const float a2 = expf(-1.f / tau_m_h2[j]);
        const float r2 = expf(-1.f / tau_adp_h2[j]);
        const float bi = b_h1h2[j] + b_h2h2[j];
        float b2v = 0.01f, s2p = 0.f;
        for (int i = 0; i < TSTEPS + 4; ++i) {
            if (i >= 2 && i <= TSTEPS + 1) {
                const int k2 = i - 2;
                uint4 sv[8];
                LOADQ(s2w, (k2 + 1) & 1, sv);              // s2(k2-1)
                const float pC = sC * (float)mvq(WQC, sv, j);
                const float in2 = pBbuf[k2 & 1][j] + pC + bi;
                b2v = r2 * b2v + (1.f - r2) * s2p;
                const float Bt = 0.01f + 1.8f * b2v;
                h2m = h2m * a2 + (1.f - a2) * in2 - Bt * s2p;
                const int sp = (h2m - Bt > 0.f) ? 1 : 0;
                s2p = (float)sp;
                const unsigned long long mk = __ballot(sp);
                const uint32_t mlo = (uint32_t)mk, mhi = (uint32_t)(mk >> 32);
                if (lane < 16) {
                    const uint32_t nib = (lane < 8 ? mlo : mhi) >> ((lane & 7) * 4);
                    s2w[k2 & 1][((w - 4) << 4) + lane] = nib2bytes(nib);
                }
            }
            __syncthreads();
        }
    } else if (w == 6) {
        // ================= RO: rdot(i-3) = W_h2o . s2(i-3) =================
        const int o = lane;
        const float sO = (o < 32) ? scO[o] : 0.f;
        for (int i = 0; i < TSTEPS + 4; ++i) {
            if (i >= 3 && i <= TSTEPS + 2 && o < ON) {
                const int k3 = i - 3;
                uint4 sv[8];
                LOADQ(s2w, k3 & 1, sv);
                rdot_lds[k3 & 1][o] = sO * (float)mvqo(WQO, sv, o);
            }
            __syncthreads();
        }
    } else {
        // ================= OM: redundant register softmax (r14) ============
        float omv[ON], accv[ON], aov[ON], bov[ON];
#pragma unroll
        for (int k = 0; k < ON; ++k) {
            omv[k]  = om0[b * ON + k];
            aov[k]  = expf(-1.f / tau_m_o[k]);
            bov[k]  = b_h2o[k];
            accv[k] = 0.f;
        }
        for (int i = 0; i < TSTEPS + 4; ++i) {
            if (i >= 4) {
                const int k4 = i - 4;
                const float4* rp = (const float4*)&rdot_lds[k4 & 1][0];
                const float4 r0 = rp[0], r1 = rp[1], r2 = rp[2], r3 = rp[3], r4 = rp[4];
                float rd[ON];
                rd[0] = r0.x;  rd[1] = r0.y;  rd[2] = r0.z;  rd[3] = r0.w;
                rd[4] = r1.x;  rd[5] = r1.y;  rd[6] = r1.z;  rd[7] = r1.w;
                rd[8] = r2.x;  rd[9] = r2.y;  rd[10] = r2.z; rd[11] = r2.w;
                rd[12] = r3.x; rd[13] = r3.y; rd[14] = r3.z; rd[15] = r3.w;
                rd[16] = r4.x; rd[17] = r4.y; rd[18] = r4.z; rd[19] = r4.w;
#pragma unroll
                for (int k = 0; k < ON; ++k)
                    omv[k] = omv[k] * aov[k] + (1.f - aov[k]) * (rd[k] + bov[k]);
                float m0 = omv[0], m1 = omv[1], m2 = omv[2], m3 = omv[3];
#pragma unroll
                for (int k = 4; k < ON; k += 4) {
                    m0 = fmaxf(m0, omv[k]);
                    m1 = fmaxf(m1, omv[k + 1]);
                    m2 = fmaxf(m2, omv[k + 2]);
                    m3 = fmaxf(m3, omv[k + 3]);
                }
                const float mx = fmaxf(fmaxf(m0, m1), fmaxf(m2, m3));
                float e[ON];
                float d0 = 0.f, d1 = 0.f, d2 = 0.f, d3 = 0.f;
#pragma unroll
                for (int k = 0; k < ON; k += 4) {
                    e[k]     = __expf(omv[k] - mx);     d0 += e[k];
                    e[k + 1] = __expf(omv[k + 1] - mx); d1 += e[k + 1];
                    e[k + 2] = __expf(omv[k + 2] - mx); d2 += e[k + 2];
                    e[k + 3] = __expf(omv[k + 3] - mx); d3 += e[k + 3];
                }
                const float den = (d0 + d1) + (d2 + d3);
                if (k4 > 10) {
                    const float rden = 1.f / den;
#pragma unroll
                    for (int k = 0; k < ON; ++k)
                        accv[k] = fmaf(e[k], rden, accv[k]);
                }
            }
            __syncthreads();
        }
        if (lane == 0) {
#pragma unroll
            for (int k = 0; k < ON; ++k) out[b * ON + k] = accv[k];
        }
    }
}

// ---------------------------------------------------------------------------
// Phase C: A_norm = sum|W_h1h1| + sum|W_h2h2|  -> out[5120]  (exact fp32)
// ---------------------------------------------------------------------------
__global__ void anorm_kernel(const float* __restrict__ W1,
                             const float* __restrict__ W2,
                             float* __restrict__ out) {
    __shared__ float red[256];
    float s = 0.f;
    for (int i = threadIdx.x; i < HN * HN; i += 256)
        s += fabsf(W1[i]) + fabsf(W2[i]);
    red[threadIdx.x] = s;
    __syncthreads();
    for (int off = 128; off > 0; off >>= 1) {
        if (threadIdx.x < off) red[threadIdx.x] += red[threadIdx.x + off];
        __syncthreads();
    }
    if (threadIdx.x == 0) out[256 * ON] = red[0];
}

extern "C" void kernel_launch(void* const* d_in, const int* in_sizes, int n_in,
                              void* d_out, int out_size, void* d_ws, size_t ws_size,
                              hipStream_t stream) {
    const float* input      = (const float*)d_in[0];
    // d_in[1], d_in[2]: A1_mask/A2_mask -- all-ones, unused by reference math
    const float* W_ih1      = (const float*)d_in[3];
    const float* b_ih1      = (const float*)d_in[4];
    const float* W_h1h1     = (const float*)d_in[5];
    const float* b_h1h1     = (const float*)d_in[6];
    const float* W_h1h2     = (const float*)d_in[7];
    const float* b_h1h2     = (const float*)d_in[8];
    const float* W_h2h2     = (const float*)d_in[9];
    const float* b_h2h2     = (const float*)d_in[10];
    const float* W_h2o      = (const float*)d_in[11];
    const float* b_h2o      = (const float*)d_in[12];
    const float* tau_adp_h1 = (const float*)d_in[13];
    const float* tau_adp_h2 = (const float*)d_in[14];
    const float* tau_m_h1   = (const float*)d_in[15];
    const float* tau_m_h2   = (const float*)d_in[16];
    const float* tau_m_o    = (const float*)d_in[17];
    const float* h1m0       = (const float*)d_in[18];
    const float* h2m0       = (const float*)d_in[19];
    const float* om0        = (const float*)d_in[20];

    float* out = (float*)d_out;
    _Float16* ffbuf = (_Float16*)d_ws;   // 256*250*128*2 = 16.4 MB

    anorm_kernel<<<1, 256, 0, stream>>>(W_h1h1, W_h2h2, out);
    ff_gemm<<<500, 256, 0, stream>>>(input, W_ih1, b_ih1, ffbuf);
    srnn_pipe14<<<256, 512, 0, stream>>>(ffbuf, W_h1h1, b_h1h1, W_h1h2, b_h1h2,
                                         W_h2h2, b_h2h2, W_h2o, b_h2o,
                                         tau_adp_h1, tau_adp_h2,
                                         tau_m_h1, tau_m_h2, tau_m_o,
                                         h1m0, h2m0, om0, out);
}